// Round 1
// baseline (23.639 us; speedup 1.0000x reference)
//
#include <hip/hip_runtime.h>

#define C   64
#define B   4096
#define CX  100
#define CY  88
#define CZ  80
#define SX  (CY * CZ)        // 7040: x stride
#define SC  (CX * CY * CZ)   // 704000: channel stride
#define MARGIN 1.0f

// One wave (64 lanes) per point; lane = channel. 4 waves per block.
__global__ void __launch_bounds__(256)
ccl_main_kernel(const float* __restrict__ fix,
                const float* __restrict__ mov,
                const int*   __restrict__ fpts,
                const int*   __restrict__ ppts,
                const int*   __restrict__ npts,
                float*       __restrict__ out,      // [0]=loss, [1..B]=pos_dis, [1+B..2B]=neg_dis
                float*       __restrict__ partial)  // [gridDim.x] block-partial loss sums
{
    const int wave = threadIdx.x >> 6;   // 0..3
    const int lane = threadIdx.x & 63;   // channel index
    const int pt   = blockIdx.x * 4 + wave;

    __shared__ float wave_loss[4];

    float contrib = 0.0f;

    if (pt < B) {
        // point_redirection: coord % crop (coords are non-negative)
        const int fx = fpts[pt * 3 + 0] % CX;
        const int fy = fpts[pt * 3 + 1] % CY;
        const int fz = fpts[pt * 3 + 2] % CZ;
        const int px = ppts[pt * 3 + 0] % CX;
        const int py = ppts[pt * 3 + 1] % CY;
        const int pz = ppts[pt * 3 + 2] % CZ;
        const int nx = npts[pt * 3 + 0] % CX;
        const int ny = npts[pt * 3 + 1] % CY;
        const int nz = npts[pt * 3 + 2] % CZ;

        const int fo = lane * SC + fx * SX + fy * CZ + fz;
        const int po = lane * SC + px * SX + py * CZ + pz;
        const int no = lane * SC + nx * SX + ny * CZ + nz;

        const float f = fix[fo];
        const float p = mov[po];
        const float n = mov[no];

        float dp = (f - p) * (f - p);
        float dn = (f - n) * (f - n);

        // wave64 butterfly reduction
        #pragma unroll
        for (int off = 32; off > 0; off >>= 1) {
            dp += __shfl_down(dp, off, 64);
            dn += __shfl_down(dn, off, 64);
        }

        if (lane == 0) {
            const float pos_dis = sqrtf(dp);
            const float neg_dis = sqrtf(dn);
            out[1 + pt]     = pos_dis;
            out[1 + B + pt] = neg_dis;
            const float t = fmaxf(0.0f, MARGIN - neg_dis);
            contrib = dp + t * t;
        }
    }

    if (lane == 0) wave_loss[wave] = contrib;
    __syncthreads();

    if (threadIdx.x == 0) {
        partial[blockIdx.x] = wave_loss[0] + wave_loss[1] + wave_loss[2] + wave_loss[3];
    }
}

// Deterministic final reduction of block partials -> loss scalar.
__global__ void __launch_bounds__(256)
ccl_reduce_kernel(const float* __restrict__ partial, int n, float* __restrict__ out)
{
    __shared__ float wsum[4];
    const int tid  = threadIdx.x;
    const int lane = tid & 63;
    const int wave = tid >> 6;

    float s = 0.0f;
    for (int i = tid; i < n; i += 256) s += partial[i];

    #pragma unroll
    for (int off = 32; off > 0; off >>= 1) s += __shfl_down(s, off, 64);

    if (lane == 0) wsum[wave] = s;
    __syncthreads();

    if (tid == 0) {
        const float total = wsum[0] + wsum[1] + wsum[2] + wsum[3];
        out[0] = total / (4.0f * (float)B) * 100.0f;
    }
}

extern "C" void kernel_launch(void* const* d_in, const int* in_sizes, int n_in,
                              void* d_out, int out_size, void* d_ws, size_t ws_size,
                              hipStream_t stream)
{
    const float* fix  = (const float*)d_in[0];
    const float* mov  = (const float*)d_in[1];
    const int*   fpts = (const int*)d_in[2];
    const int*   ppts = (const int*)d_in[3];
    const int*   npts = (const int*)d_in[4];
    float* out = (float*)d_out;
    float* partial = (float*)d_ws;

    const int nblocks = B / 4;  // 1024 blocks, 1 wave per point

    ccl_main_kernel<<<nblocks, 256, 0, stream>>>(fix, mov, fpts, ppts, npts, out, partial);
    ccl_reduce_kernel<<<1, 256, 0, stream>>>(partial, nblocks, out);
}